// Round 1
// baseline (841.366 us; speedup 1.0000x reference)
//
#include <hip/hip_runtime.h>

// Problem constants
#define BB        16
#define HH        6
#define WW        4096
#define CC        128
#define TT        1024          // W/OVERLAP
#define NTOK      16384         // B*T
#define FIX       768           // H*C
#define HID       1024
#define CBK       1024
#define CBD       8
#define NPVQ      3
#define NRVQ      6
#define ZQ_SIZE   50331648ull   // B*H*W*C

// ws layout (byte offsets), all 8-aligned
#define OFF_ACC   0ull                           // 16 B   loss accumulator (double)
#define OFF_EN    16ull                          // 18*1024*8 doubles = 1179648 B
#define OFF_HE    (16ull + 1179648ull)           // 18*1024 doubles   = 147456 B
#define OFF_R     (OFF_HE + 147456ull)           // 3*16384*8 doubles = 3145728 B
#define OFF_ZQ    (OFF_R + 3145728ull)           // 3*16384*8 floats  = 1572864 B

// ---------------------------------------------------------------------------
// Kernel A: l2-normalize all 18 codebooks into fp64 table, plus 0.5*||e||^2
// ---------------------------------------------------------------------------
__global__ __launch_bounds__(256) void knorm(const float* __restrict__ emb,
                                             double* __restrict__ en,
                                             double* __restrict__ he) {
    int gid = blockIdx.x * 256 + threadIdx.x;
    if (gid >= NPVQ * NRVQ * CBK) return;
    const float* e = emb + (size_t)gid * CBD;
    double v[CBD];
    double s = 0.0;
#pragma unroll
    for (int d = 0; d < CBD; ++d) { v[d] = (double)e[d]; s += v[d] * v[d]; }
    double n = fmax(sqrt(s), 1e-12);
    double s2 = 0.0;
#pragma unroll
    for (int d = 0; d < CBD; ++d) {
        double q = v[d] / n;
        en[(size_t)gid * CBD + d] = q;
        s2 += q * q;
    }
    he[gid] = 0.5 * s2;
}

// ---------------------------------------------------------------------------
// Kernel B: transpose-gather one token (12 KB) into LDS, project 1024->8 (fp64)
//   x[b,t, o*768 + c*6 + h] = z_e[b, h*4096 + t*4 + o, c]
//   r[m][d] = sum_j x[m*1024+j] * pd[m][j][d]
// ---------------------------------------------------------------------------
__global__ __launch_bounds__(256) void kproj(const float* __restrict__ ze,
                                             const float* __restrict__ pd,
                                             double* __restrict__ r_ws) {
    __shared__ float x[NPVQ * HID];  // 3072 floats, f-order
    const int tok = blockIdx.x;
    const int b = tok >> 10, t = tok & 1023;
    const int tid = threadIdx.x;
    const size_t zbase = (size_t)b * (HH * WW * CC);
#pragma unroll
    for (int q = 0; q < 12; ++q) {
        int idx = tid + 256 * q;               // (h,o,c) linear
        int h = idx >> 9, rem = idx & 511, o = rem >> 7, c = rem & 127;
        float v = ze[zbase + (size_t)(h * WW + t * 4 + o) * CC + c];
        x[o * FIX + c * HH + h] = v;
    }
    __syncthreads();
    const int w = tid >> 6, l = tid & 63;
    if (w < NPVQ) {
        const int m = w;
        double acc[CBD] = {0, 0, 0, 0, 0, 0, 0, 0};
        for (int q = 0; q < 16; ++q) {
            int j = l + 64 * q;
            double xv = (double)x[m * HID + j];
            const float* pr = pd + (size_t)(m * HID + j) * CBD;
#pragma unroll
            for (int d = 0; d < CBD; ++d) acc[d] = fma(xv, (double)pr[d], acc[d]);
        }
#pragma unroll
        for (int off = 32; off >= 1; off >>= 1) {
#pragma unroll
            for (int d = 0; d < CBD; ++d) acc[d] += __shfl_down(acc[d], off, 64);
        }
        if (l == 0) {
            double* rp = r_ws + ((size_t)m * NTOK + tok) * CBD;
#pragma unroll
            for (int d = 0; d < CBD; ++d) rp[d] = acc[d];
        }
    }
}

// ---------------------------------------------------------------------------
// Kernel C: residual VQ, fp64. Block = (m, 64-token group). lane=token,
// wave scans a 256-code quarter; cross-wave argmin merge per stream with
// first-occurrence tie-breaking (matches np.argmin).
// ---------------------------------------------------------------------------
__global__ __launch_bounds__(256) void kvq(const double* __restrict__ en_all,
                                           const double* __restrict__ he_all,
                                           const double* __restrict__ r_ws,
                                           float* __restrict__ zq_ws,
                                           float* __restrict__ out,      // d_out base
                                           const int* __restrict__ nsp,
                                           double* __restrict__ accum) {
    const int blk = blockIdx.x;
    const int m = blk >> 8, g = blk & 255;
    const int tid = threadIdx.x;
    const int w = tid >> 6, l = tid & 63;
    const int tok = g * 64 + l;
    const int b = tok >> 10, t = tok & 1023;
    const int ns = *nsp;

    __shared__ double lds_d[256];
    __shared__ int    lds_k[256];

    double r[CBD];
    {
        const double* rp = r_ws + ((size_t)m * NTOK + tok) * CBD;
#pragma unroll
        for (int d = 0; d < CBD; ++d) r[d] = rp[d];
    }
    double zq[CBD] = {0, 0, 0, 0, 0, 0, 0, 0};
    double loss = 0.0;

    for (int i = 0; i < ns; ++i) {
        const double* en = en_all + ((size_t)(m * NRVQ + i)) * CBK * CBD;
        const double* he = he_all + ((size_t)(m * NRVQ + i)) * CBK;
        // z = l2n(r) in fp64
        double s = 0.0;
#pragma unroll
        for (int d = 0; d < CBD; ++d) s += r[d] * r[d];
        double n = fmax(sqrt(s), 1e-12);
        double z[CBD];
#pragma unroll
        for (int d = 0; d < CBD; ++d) z[d] = r[d] / n;

        double best = 1e300;
        int bk = 0;
        const int k0 = w * 256;
        for (int k = k0; k < k0 + 256; ++k) {
            const double* ev = en + (size_t)k * CBD;
            double dot = 0.0;
#pragma unroll
            for (int d = 0; d < CBD; ++d) dot = fma(z[d], ev[d], dot);
            double dist = he[k] - dot;   // argmin-equivalent to full cdist
            if (dist < best) { best = dist; bk = k; }  // strict <: first min
        }
        lds_d[w * 64 + l] = best;
        lds_k[w * 64 + l] = bk;
        __syncthreads();
        double bb = lds_d[l];
        int bbk = lds_k[l];
#pragma unroll
        for (int w2 = 1; w2 < 4; ++w2) {
            double d2 = lds_d[w2 * 64 + l];
            if (d2 < bb) { bb = d2; bbk = lds_k[w2 * 64 + l]; }  // asc k-ranges
        }
        const double* qv = en + (size_t)bbk * CBD;
        if (w == 0) {
            double ls = 0.0;
#pragma unroll
            for (int d = 0; d < CBD; ++d) { double df = qv[d] - r[d]; ls += df * df; }
            loss += ls;
            out[ZQ_SIZE + ((size_t)(b * ns + i) * NPVQ + m) * TT + t] = (float)bbk;
        }
#pragma unroll
        for (int d = 0; d < CBD; ++d) { double q = qv[d]; r[d] -= q; zq[d] += q; }
        __syncthreads();   // lds_d/lds_k reused next stream
    }

    if (w == 0) {
        float* zp = zq_ws + ((size_t)m * NTOK + tok) * CBD;
#pragma unroll
        for (int d = 0; d < CBD; ++d) zp[d] = (float)zq[d];
#pragma unroll
        for (int off = 32; off >= 1; off >>= 1) loss += __shfl_down(loss, off, 64);
        if (l == 0) atomicAdd(accum, loss);
    }
}

// ---------------------------------------------------------------------------
// Kernel D: up-projection 8->1024 + inverse permutation scatter (coalesced),
// plus loss epilogue. Block = 32 consecutive tokens.
// ---------------------------------------------------------------------------
__global__ __launch_bounds__(256) void kout(const float* __restrict__ pu,
                                            const float* __restrict__ zq_ws,
                                            float* __restrict__ out,
                                            const int* __restrict__ nsp,
                                            const double* __restrict__ accum) {
    __shared__ float zl[32][NPVQ][CBD];   // 3 KB
    const int blk = blockIdx.x;
    const int tok0 = blk * 32;
    const int b = tok0 >> 10, t0 = tok0 & 1023;
    const int tid = threadIdx.x;
#pragma unroll
    for (int q = 0; q < 3; ++q) {
        int ii = tid + 256 * q;            // [0,768)
        int mm = ii >> 8, rem = ii & 255, tt = rem >> 3, d = rem & 7;
        zl[tt][mm][d] = zq_ws[((size_t)mm * NTOK + tok0 + tt) * CBD + d];
    }
    __syncthreads();
    const size_t obase = (size_t)b * (HH * WW * CC);
#pragma unroll 2
    for (int q = 0; q < 12; ++q) {
        int idx = tid + 256 * q;           // (h,o,c) linear
        int h = idx >> 9, rem = idx & 511, o = rem >> 7, c = rem & 127;
        int f = o * FIX + c * HH + h;
        int m = f >> 10, j = f & 1023;
        float pu8[CBD];
#pragma unroll
        for (int d = 0; d < CBD; ++d) pu8[d] = pu[((size_t)(m * CBD + d)) * HID + j];
        size_t rowbase = obase + ((size_t)h * WW + t0 * 4 + o) * CC + c;
        for (int tt = 0; tt < 32; ++tt) {
            float y = 0.0f;
#pragma unroll
            for (int d = 0; d < CBD; ++d) y = fmaf(zl[tt][m][d], pu8[d], y);
            out[rowbase + (size_t)tt * 4 * CC] = y;
        }
    }
    if (blk == 0 && tid == 0) {
        int ns = *nsp;
        double s = *accum;
        float lv = (float)(s / (double)(NTOK * CBD * NPVQ));
        size_t lbase = ZQ_SIZE + (size_t)BB * ns * NPVQ * TT;
        out[lbase] = lv;       // cb_loss / 3
        out[lbase + 1] = lv;   // cm_loss / 3 (numerically identical)
    }
}

// ---------------------------------------------------------------------------
extern "C" void kernel_launch(void* const* d_in, const int* in_sizes, int n_in,
                              void* d_out, int out_size, void* d_ws, size_t ws_size,
                              hipStream_t stream) {
    const float* ze  = (const float*)d_in[0];
    const float* emb = (const float*)d_in[1];
    const float* pd  = (const float*)d_in[2];
    const float* pu  = (const float*)d_in[3];
    const int*   nsp = (const int*)d_in[4];
    float* out = (float*)d_out;
    char* ws = (char*)d_ws;

    double* accum = (double*)(ws + OFF_ACC);
    double* en    = (double*)(ws + OFF_EN);
    double* he    = (double*)(ws + OFF_HE);
    double* r_ws  = (double*)(ws + OFF_R);
    float*  zq_ws = (float*)(ws + OFF_ZQ);

    hipMemsetAsync(accum, 0, 16, stream);
    knorm<<<(NPVQ * NRVQ * CBK + 255) / 256, 256, 0, stream>>>(emb, en, he);
    kproj<<<NTOK, 256, 0, stream>>>(ze, pd, r_ws);
    kvq<<<NPVQ * (NTOK / 64), 256, 0, stream>>>(en, he, r_ws, zq_ws, out, nsp, accum);
    kout<<<NTOK / 32, 256, 0, stream>>>(pu, zq_ws, out, nsp, accum);
}

// Round 2
// 747.109 us; speedup vs baseline: 1.1262x; 1.1262x over previous
//
#include <hip/hip_runtime.h>

// Problem constants
#define BB        16
#define HH        6
#define WW        4096
#define CC        128
#define TT        1024          // W/OVERLAP
#define NTOK      16384         // B*T
#define FIX       768           // H*C
#define HID       1024
#define CBK       1024
#define CBD       8
#define NPVQ      3
#define NRVQ      6
#define ZQ_SIZE   50331648ull   // B*H*W*C

// ws layout (byte offsets), all 8-aligned
#define OFF_ACC   0ull                           // 16 B   loss accumulator (double)
#define OFF_EN    16ull                          // 18*1024*8 doubles = 1179648 B
#define OFF_R     (OFF_EN + 1179648ull)          // 3*16384*8 doubles = 3145728 B
#define OFF_ZQ    (OFF_R + 3145728ull)           // 3*16384*8 floats  = 1572864 B

// ---------------------------------------------------------------------------
// Kernel A: l2-normalize all 18 codebooks into fp64 table
// ---------------------------------------------------------------------------
__global__ __launch_bounds__(256) void knorm(const float* __restrict__ emb,
                                             double* __restrict__ en) {
    int gid = blockIdx.x * 256 + threadIdx.x;
    if (gid >= NPVQ * NRVQ * CBK) return;
    const float* e = emb + (size_t)gid * CBD;
    double v[CBD];
    double s = 0.0;
#pragma unroll
    for (int d = 0; d < CBD; ++d) { v[d] = (double)e[d]; s += v[d] * v[d]; }
    double n = fmax(sqrt(s), 1e-12);
#pragma unroll
    for (int d = 0; d < CBD; ++d) en[(size_t)gid * CBD + d] = v[d] / n;
}

// ---------------------------------------------------------------------------
// Kernel B: transpose-gather one token (12 KB) into LDS, project 1024->8 (fp64)
//   x[b,t, o*768 + c*6 + h] = z_e[b, h*4096 + t*4 + o, c]
//   r[m][d] = sum_j x[m*1024+j] * pd[m][j][d]
// ---------------------------------------------------------------------------
__global__ __launch_bounds__(256) void kproj(const float* __restrict__ ze,
                                             const float* __restrict__ pd,
                                             double* __restrict__ r_ws) {
    __shared__ float x[NPVQ * HID];  // 3072 floats, f-order
    const int tok = blockIdx.x;
    const int b = tok >> 10, t = tok & 1023;
    const int tid = threadIdx.x;
    const size_t zbase = (size_t)b * (HH * WW * CC);
#pragma unroll
    for (int q = 0; q < 12; ++q) {
        int idx = tid + 256 * q;               // (h,o,c) linear
        int h = idx >> 9, rem = idx & 511, o = rem >> 7, c = rem & 127;
        float v = ze[zbase + (size_t)(h * WW + t * 4 + o) * CC + c];
        x[o * FIX + c * HH + h] = v;
    }
    __syncthreads();
    const int w = tid >> 6, l = tid & 63;
    if (w < NPVQ) {
        const int m = w;
        double acc[CBD] = {0, 0, 0, 0, 0, 0, 0, 0};
        for (int q = 0; q < 16; ++q) {
            int j = l + 64 * q;
            double xv = (double)x[m * HID + j];
            const float* pr = pd + (size_t)(m * HID + j) * CBD;
#pragma unroll
            for (int d = 0; d < CBD; ++d) acc[d] = fma(xv, (double)pr[d], acc[d]);
        }
#pragma unroll
        for (int off = 32; off >= 1; off >>= 1) {
#pragma unroll
            for (int d = 0; d < CBD; ++d) acc[d] += __shfl_down(acc[d], off, 64);
        }
        if (l == 0) {
            double* rp = r_ws + ((size_t)m * NTOK + tok) * CBD;
#pragma unroll
            for (int d = 0; d < CBD; ++d) rp[d] = acc[d];
        }
    }
}

// ---------------------------------------------------------------------------
// Kernel C: residual VQ, fp64. Block = (m, 64-token group), 8 waves.
// lane = token; wave scans a 128-code slice with unroll-4 ILP; cross-wave
// argmax merge in LDS with first-occurrence tie-breaking (== np.argmin since
// dist = const - dot, codes slices ascending).
// ---------------------------------------------------------------------------
#define KV_WAVES   8
#define KV_THREADS (KV_WAVES * 64)
#define KV_SLICE   (CBK / KV_WAVES)   // 128

__global__ __launch_bounds__(KV_THREADS) void kvq(const double* __restrict__ en_all,
                                                  const double* __restrict__ r_ws,
                                                  float* __restrict__ zq_ws,
                                                  float* __restrict__ out,     // d_out base
                                                  const int* __restrict__ nsp,
                                                  double* __restrict__ accum) {
    const int blk = blockIdx.x;
    const int m = blk >> 8, g = blk & 255;
    const int tid = threadIdx.x;
    const int w = tid >> 6, l = tid & 63;
    const int tok = g * 64 + l;
    const int b = tok >> 10, t = tok & 1023;
    const int ns = *nsp;

    __shared__ double lds_d[KV_THREADS];
    __shared__ int    lds_k[KV_THREADS];

    double r[CBD];
    {
        const double* rp = r_ws + ((size_t)m * NTOK + tok) * CBD;
#pragma unroll
        for (int d = 0; d < CBD; ++d) r[d] = rp[d];
    }
    double zq[CBD] = {0, 0, 0, 0, 0, 0, 0, 0};
    double loss = 0.0;

    const int k0 = w * KV_SLICE;
    for (int i = 0; i < ns; ++i) {
        const double* en = en_all + ((size_t)(m * NRVQ + i)) * CBK * CBD;
        // argmax_k dot(r, e_k)  (== argmin of cdist: positive-scale + const invariant)
        double best = -1e300;
        int bk = k0;
        for (int k = k0; k < k0 + KV_SLICE; k += 4) {
            double dots[4];
#pragma unroll
            for (int u = 0; u < 4; ++u) {
                const double* ev = en + (size_t)(k + u) * CBD;
                double a0 = 0.0, a1 = 0.0;
#pragma unroll
                for (int d = 0; d < CBD; d += 2) {
                    a0 = fma(r[d], ev[d], a0);
                    a1 = fma(r[d + 1], ev[d + 1], a1);
                }
                dots[u] = a0 + a1;
            }
#pragma unroll
            for (int u = 0; u < 4; ++u) {
                if (dots[u] > best) { best = dots[u]; bk = k + u; }  // strict >: first max
            }
        }
        lds_d[tid] = best;
        lds_k[tid] = bk;
        __syncthreads();
        double bb = lds_d[l];
        int bbk = lds_k[l];
#pragma unroll
        for (int w2 = 1; w2 < KV_WAVES; ++w2) {
            double d2 = lds_d[w2 * 64 + l];
            if (d2 > bb) { bb = d2; bbk = lds_k[w2 * 64 + l]; }  // ascending k-slices
        }
        const double* qv = en + (size_t)bbk * CBD;
        if (w == 0) {
            double ls = 0.0;
#pragma unroll
            for (int d = 0; d < CBD; ++d) { double df = qv[d] - r[d]; ls += df * df; }
            loss += ls;
            out[ZQ_SIZE + ((size_t)(b * ns + i) * NPVQ + m) * TT + t] = (float)bbk;
        }
#pragma unroll
        for (int d = 0; d < CBD; ++d) { double q = qv[d]; r[d] -= q; zq[d] += q; }
        __syncthreads();   // lds_d/lds_k reused next stream
    }

    if (w == 0) {
        float* zp = zq_ws + ((size_t)m * NTOK + tok) * CBD;
#pragma unroll
        for (int d = 0; d < CBD; ++d) zp[d] = (float)zq[d];
#pragma unroll
        for (int off = 32; off >= 1; off >>= 1) loss += __shfl_down(loss, off, 64);
        if (l == 0) atomicAdd(accum, loss);
    }
}

// ---------------------------------------------------------------------------
// Kernel D: up-projection 8->1024 + inverse permutation scatter (coalesced),
// plus loss epilogue. Block = 32 consecutive tokens.
// ---------------------------------------------------------------------------
__global__ __launch_bounds__(256) void kout(const float* __restrict__ pu,
                                            const float* __restrict__ zq_ws,
                                            float* __restrict__ out,
                                            const int* __restrict__ nsp,
                                            const double* __restrict__ accum) {
    __shared__ float zl[32][NPVQ][CBD];   // 3 KB
    const int blk = blockIdx.x;
    const int tok0 = blk * 32;
    const int b = tok0 >> 10, t0 = tok0 & 1023;
    const int tid = threadIdx.x;
#pragma unroll
    for (int q = 0; q < 3; ++q) {
        int ii = tid + 256 * q;            // [0,768)
        int mm = ii >> 8, rem = ii & 255, tt = rem >> 3, d = rem & 7;
        zl[tt][mm][d] = zq_ws[((size_t)mm * NTOK + tok0 + tt) * CBD + d];
    }
    __syncthreads();
    const size_t obase = (size_t)b * (HH * WW * CC);
#pragma unroll 2
    for (int q = 0; q < 12; ++q) {
        int idx = tid + 256 * q;           // (h,o,c) linear
        int h = idx >> 9, rem = idx & 511, o = rem >> 7, c = rem & 127;
        int f = o * FIX + c * HH + h;
        int m = f >> 10, j = f & 1023;
        float pu8[CBD];
#pragma unroll
        for (int d = 0; d < CBD; ++d) pu8[d] = pu[((size_t)(m * CBD + d)) * HID + j];
        size_t rowbase = obase + ((size_t)h * WW + t0 * 4 + o) * CC + c;
        for (int tt = 0; tt < 32; ++tt) {
            float y = 0.0f;
#pragma unroll
            for (int d = 0; d < CBD; ++d) y = fmaf(zl[tt][m][d], pu8[d], y);
            out[rowbase + (size_t)tt * 4 * CC] = y;
        }
    }
    if (blk == 0 && tid == 0) {
        int ns = *nsp;
        double s = *accum;
        float lv = (float)(s / (double)(NTOK * CBD * NPVQ));
        size_t lbase = ZQ_SIZE + (size_t)BB * ns * NPVQ * TT;
        out[lbase] = lv;       // cb_loss / 3
        out[lbase + 1] = lv;   // cm_loss / 3 (numerically identical)
    }
}

// ---------------------------------------------------------------------------
extern "C" void kernel_launch(void* const* d_in, const int* in_sizes, int n_in,
                              void* d_out, int out_size, void* d_ws, size_t ws_size,
                              hipStream_t stream) {
    const float* ze  = (const float*)d_in[0];
    const float* emb = (const float*)d_in[1];
    const float* pd  = (const float*)d_in[2];
    const float* pu  = (const float*)d_in[3];
    const int*   nsp = (const int*)d_in[4];
    float* out = (float*)d_out;
    char* ws = (char*)d_ws;

    double* accum = (double*)(ws + OFF_ACC);
    double* en    = (double*)(ws + OFF_EN);
    double* r_ws  = (double*)(ws + OFF_R);
    float*  zq_ws = (float*)(ws + OFF_ZQ);

    hipMemsetAsync(accum, 0, 16, stream);
    knorm<<<(NPVQ * NRVQ * CBK + 255) / 256, 256, 0, stream>>>(emb, en);
    kproj<<<NTOK, 256, 0, stream>>>(ze, pd, r_ws);
    kvq<<<NPVQ * (NTOK / 64), KV_THREADS, 0, stream>>>(en, r_ws, zq_ws, out, nsp, accum);
    kout<<<NTOK / 32, 256, 0, stream>>>(pu, zq_ws, out, nsp, accum);
}

// Round 3
// 386.763 us; speedup vs baseline: 2.1754x; 1.9317x over previous
//
#include <hip/hip_runtime.h>

// Problem constants
#define BB        16
#define HH        6
#define WW        4096
#define CC        128
#define TT        1024          // W/OVERLAP
#define NTOK      16384         // B*T
#define FIX       768           // H*C
#define HID       1024
#define CBK       1024
#define CBD       8
#define NPVQ      3
#define NRVQ      6
#define ZQ_SIZE   50331648ull   // B*H*W*C

// ws layout (byte offsets), all 8-aligned
#define OFF_ACC   0ull                           // 16 B   loss accumulator (double)
#define OFF_EN    16ull                          // 18*1024*8 doubles = 1179648 B
#define OFF_R     (OFF_EN + 1179648ull)          // 3*16384*8 doubles = 3145728 B
#define OFF_ZQ    (OFF_R + 3145728ull)           // 3*16384*8 floats  = 1572864 B

// ---------------------------------------------------------------------------
// Kernel A: l2-normalize all 18 codebooks into fp64 table
// ---------------------------------------------------------------------------
__global__ __launch_bounds__(256) void knorm(const float* __restrict__ emb,
                                             double* __restrict__ en) {
    int gid = blockIdx.x * 256 + threadIdx.x;
    if (gid >= NPVQ * NRVQ * CBK) return;
    const float* e = emb + (size_t)gid * CBD;
    double v[CBD];
    double s = 0.0;
#pragma unroll
    for (int d = 0; d < CBD; ++d) { v[d] = (double)e[d]; s += v[d] * v[d]; }
    double n = fmax(sqrt(s), 1e-12);
#pragma unroll
    for (int d = 0; d < CBD; ++d) en[(size_t)gid * CBD + d] = v[d] / n;
}

// ---------------------------------------------------------------------------
// Kernel B: transpose-gather one token (12 KB) into LDS, project 1024->8 (fp64)
// ---------------------------------------------------------------------------
__global__ __launch_bounds__(256) void kproj(const float* __restrict__ ze,
                                             const float* __restrict__ pd,
                                             double* __restrict__ r_ws) {
    __shared__ float x[NPVQ * HID];  // 3072 floats, f-order
    const int tok = blockIdx.x;
    const int b = tok >> 10, t = tok & 1023;
    const int tid = threadIdx.x;
    const size_t zbase = (size_t)b * (HH * WW * CC);
#pragma unroll
    for (int q = 0; q < 12; ++q) {
        int idx = tid + 256 * q;               // (h,o,c) linear
        int h = idx >> 9, rem = idx & 511, o = rem >> 7, c = rem & 127;
        float v = ze[zbase + (size_t)(h * WW + t * 4 + o) * CC + c];
        x[o * FIX + c * HH + h] = v;
    }
    __syncthreads();
    const int w = tid >> 6, l = tid & 63;
    if (w < NPVQ) {
        const int m = w;
        double acc[CBD] = {0, 0, 0, 0, 0, 0, 0, 0};
        for (int q = 0; q < 16; ++q) {
            int j = l + 64 * q;
            double xv = (double)x[m * HID + j];
            const float* pr = pd + (size_t)(m * HID + j) * CBD;
#pragma unroll
            for (int d = 0; d < CBD; ++d) acc[d] = fma(xv, (double)pr[d], acc[d]);
        }
#pragma unroll
        for (int off = 32; off >= 1; off >>= 1) {
#pragma unroll
            for (int d = 0; d < CBD; ++d) acc[d] += __shfl_down(acc[d], off, 64);
        }
        if (l == 0) {
            double* rp = r_ws + ((size_t)m * NTOK + tok) * CBD;
#pragma unroll
            for (int d = 0; d < CBD; ++d) rp[d] = acc[d];
        }
    }
}

// ---------------------------------------------------------------------------
// Kernel C: residual VQ, fp64, LDS-staged codebook.
// Block = (m, 64-token group), 8 waves, 512 thr. All 8 waves hold the same 64
// tokens (lane = token); each wave scans a 64-code slice of each 512-code
// staged half. Codebook staged in two 32 KB halves per stream -> LDS 38.9 KB
// -> 4 blocks/CU (32 waves/CU). Scan reads are wave-uniform LDS broadcasts
// (conflict-free, fine-grained lgkmcnt). Cross-wave argmax merge with explicit
// index tie-break (== np.argmin first-occurrence on dist = const - dot).
// ---------------------------------------------------------------------------
#define KV_WAVES   8
#define KV_THREADS (KV_WAVES * 64)
#define KV_HALF    512                 // codes staged per phase
#define KV_WSLICE  (KV_HALF / KV_WAVES)  // 64 codes per wave per phase

__global__ __launch_bounds__(KV_THREADS) void kvq(const double* __restrict__ en_all,
                                                  const double* __restrict__ r_ws,
                                                  float* __restrict__ zq_ws,
                                                  float* __restrict__ out,     // d_out base
                                                  const int* __restrict__ nsp,
                                                  double* __restrict__ accum) {
    __shared__ __align__(16) double tbl[KV_HALF * CBD];  // 32 KB
    __shared__ double lds_d[KV_THREADS];                 // 4 KB
    __shared__ int    lds_k[KV_THREADS];                 // 2 KB

    const int blk = blockIdx.x;
    const int m = blk >> 8, g = blk & 255;
    const int tid = threadIdx.x;
    const int w = tid >> 6, l = tid & 63;
    const int tok = g * 64 + l;
    const int b = tok >> 10, t = tok & 1023;
    const int ns = *nsp;

    double r[CBD];
    {
        const double* rp = r_ws + ((size_t)m * NTOK + tok) * CBD;
#pragma unroll
        for (int d = 0; d < CBD; ++d) r[d] = rp[d];
    }
    double zq[CBD] = {0, 0, 0, 0, 0, 0, 0, 0};
    double loss = 0.0;

    const int kl0 = w * KV_WSLICE;
    for (int i = 0; i < ns; ++i) {
        const double* en = en_all + ((size_t)(m * NRVQ + i)) * CBK * CBD;
        // argmax_k dot(r, e_k)  (== argmin of cdist: positive-scale + const invariant)
        double best = -1e300;
        int bk = 0;
#pragma unroll
        for (int p = 0; p < 2; ++p) {
            __syncthreads();   // table free (prev phase/stream scans complete)
            {   // stage 512 codes (32 KB) cooperatively, coalesced float4
                const float4* src = (const float4*)(en + (size_t)p * KV_HALF * CBD);
                float4* dst = (float4*)tbl;
#pragma unroll
                for (int q = 0; q < 4; ++q) dst[tid + KV_THREADS * q] = src[tid + KV_THREADS * q];
            }
            __syncthreads();   // table ready
            const int kg0 = p * KV_HALF;
            for (int k = kl0; k < kl0 + KV_WSLICE; k += 4) {
                double dots[4];
#pragma unroll
                for (int u = 0; u < 4; ++u) {
                    const double* ev = tbl + (size_t)(k + u) * CBD;
                    double a0 = 0.0, a1 = 0.0;
#pragma unroll
                    for (int d = 0; d < CBD; d += 2) {
                        a0 = fma(r[d], ev[d], a0);
                        a1 = fma(r[d + 1], ev[d + 1], a1);
                    }
                    dots[u] = a0 + a1;
                }
#pragma unroll
                for (int u = 0; u < 4; ++u) {
                    // strict >: first max within the wave's ascending (p,k) order
                    if (dots[u] > best) { best = dots[u]; bk = kg0 + k + u; }
                }
            }
        }
        lds_d[tid] = best;
        lds_k[tid] = bk;
        __syncthreads();
        double bb = lds_d[l];
        int bbk = lds_k[l];
#pragma unroll
        for (int w2 = 1; w2 < KV_WAVES; ++w2) {
            double d2 = lds_d[w2 * 64 + l];
            int    k2 = lds_k[w2 * 64 + l];
            // wave slices are interleaved across phases -> explicit index tie-break
            if (d2 > bb || (d2 == bb && k2 < bbk)) { bb = d2; bbk = k2; }
        }
        // winner vector: divergent gather from global (L2-resident), once/stream
        const double* qv = en + (size_t)bbk * CBD;
        if (w == 0) {
            double ls = 0.0;
#pragma unroll
            for (int d = 0; d < CBD; ++d) { double df = qv[d] - r[d]; ls += df * df; }
            loss += ls;
            out[ZQ_SIZE + ((size_t)(b * ns + i) * NPVQ + m) * TT + t] = (float)bbk;
        }
#pragma unroll
        for (int d = 0; d < CBD; ++d) { double q = qv[d]; r[d] -= q; zq[d] += q; }
    }

    if (w == 0) {
        float* zp = zq_ws + ((size_t)m * NTOK + tok) * CBD;
#pragma unroll
        for (int d = 0; d < CBD; ++d) zp[d] = (float)zq[d];
#pragma unroll
        for (int off = 32; off >= 1; off >>= 1) loss += __shfl_down(loss, off, 64);
        if (l == 0) atomicAdd(accum, loss);
    }
}

// ---------------------------------------------------------------------------
// Kernel D: up-projection 8->1024 + inverse permutation scatter (coalesced),
// plus loss epilogue. Block = 32 consecutive tokens.
// ---------------------------------------------------------------------------
__global__ __launch_bounds__(256) void kout(const float* __restrict__ pu,
                                            const float* __restrict__ zq_ws,
                                            float* __restrict__ out,
                                            const int* __restrict__ nsp,
                                            const double* __restrict__ accum) {
    __shared__ float zl[32][NPVQ][CBD];   // 3 KB
    const int blk = blockIdx.x;
    const int tok0 = blk * 32;
    const int b = tok0 >> 10, t0 = tok0 & 1023;
    const int tid = threadIdx.x;
#pragma unroll
    for (int q = 0; q < 3; ++q) {
        int ii = tid + 256 * q;            // [0,768)
        int mm = ii >> 8, rem = ii & 255, tt = rem >> 3, d = rem & 7;
        zl[tt][mm][d] = zq_ws[((size_t)mm * NTOK + tok0 + tt) * CBD + d];
    }
    __syncthreads();
    const size_t obase = (size_t)b * (HH * WW * CC);
#pragma unroll 2
    for (int q = 0; q < 12; ++q) {
        int idx = tid + 256 * q;           // (h,o,c) linear
        int h = idx >> 9, rem = idx & 511, o = rem >> 7, c = rem & 127;
        int f = o * FIX + c * HH + h;
        int m = f >> 10, j = f & 1023;
        float pu8[CBD];
#pragma unroll
        for (int d = 0; d < CBD; ++d) pu8[d] = pu[((size_t)(m * CBD + d)) * HID + j];
        size_t rowbase = obase + ((size_t)h * WW + t0 * 4 + o) * CC + c;
        for (int tt = 0; tt < 32; ++tt) {
            float y = 0.0f;
#pragma unroll
            for (int d = 0; d < CBD; ++d) y = fmaf(zl[tt][m][d], pu8[d], y);
            out[rowbase + (size_t)tt * 4 * CC] = y;
        }
    }
    if (blk == 0 && tid == 0) {
        int ns = *nsp;
        double s = *accum;
        float lv = (float)(s / (double)(NTOK * CBD * NPVQ));
        size_t lbase = ZQ_SIZE + (size_t)BB * ns * NPVQ * TT;
        out[lbase] = lv;       // cb_loss / 3
        out[lbase + 1] = lv;   // cm_loss / 3 (numerically identical)
    }
}

// ---------------------------------------------------------------------------
extern "C" void kernel_launch(void* const* d_in, const int* in_sizes, int n_in,
                              void* d_out, int out_size, void* d_ws, size_t ws_size,
                              hipStream_t stream) {
    const float* ze  = (const float*)d_in[0];
    const float* emb = (const float*)d_in[1];
    const float* pd  = (const float*)d_in[2];
    const float* pu  = (const float*)d_in[3];
    const int*   nsp = (const int*)d_in[4];
    float* out = (float*)d_out;
    char* ws = (char*)d_ws;

    double* accum = (double*)(ws + OFF_ACC);
    double* en    = (double*)(ws + OFF_EN);
    double* r_ws  = (double*)(ws + OFF_R);
    float*  zq_ws = (float*)(ws + OFF_ZQ);

    hipMemsetAsync(accum, 0, 16, stream);
    knorm<<<(NPVQ * NRVQ * CBK + 255) / 256, 256, 0, stream>>>(emb, en);
    kproj<<<NTOK, 256, 0, stream>>>(ze, pd, r_ws);
    kvq<<<NPVQ * (NTOK / 64), KV_THREADS, 0, stream>>>(en, r_ws, zq_ws, out, nsp, accum);
    kout<<<NTOK / 32, 256, 0, stream>>>(pu, zq_ws, out, nsp, accum);
}